// Round 9
// baseline (283.855 us; speedup 1.0000x reference)
//
#include <hip/hip_runtime.h>

typedef __bf16 bf16;
typedef _Float16 f16;
typedef __bf16 bf16x8 __attribute__((ext_vector_type(8)));
typedef _Float16 f16x8 __attribute__((ext_vector_type(8)));
typedef float  f32x4  __attribute__((ext_vector_type(4)));

#define B_  8
#define N_  2048
#define F_  256
#define NTOK (B_ * N_)
#define NW   (F_ * F_)              // 65,536 W elements
static constexpr float LOG2E = 1.44269504088896f;

// ---------------------------------------------------------------------------
// dtype detector (bf16-packed vs fp32). Wave-uniform. Proven rounds 3-7.
// ---------------------------------------------------------------------------
__device__ __forceinline__ int detect_bf16(const void* h) {
    const unsigned* hw = (const unsigned*)h;
    unsigned w = hw[threadIdx.x & 63];
    unsigned ex = (w >> 7) & 0xFFu;
    unsigned long long b = __ballot(ex > 100u && ex < 150u);
    return __popcll(b) >= 40;
}

__device__ __forceinline__ float ldf(const void* p, int i, int isb) {
    return isb ? (float)((const bf16*)p)[i] : ((const float*)p)[i];
}

__device__ __forceinline__ bf16x8 cvt8(const float* p) {
    float4 a = *(const float4*)p;
    float4 b = *(const float4*)(p + 4);
    bf16x8 r;
    r[0]=(bf16)a.x; r[1]=(bf16)a.y; r[2]=(bf16)a.z; r[3]=(bf16)a.w;
    r[4]=(bf16)b.x; r[5]=(bf16)b.y; r[6]=(bf16)b.z; r[7]=(bf16)b.w;
    return r;
}

// WhT2 tiled layout (LDS-bank-XOR baked in), byte address for (b, f, n):
//   tile = b*32 + (n>>6); within tile: row f (128 B), phys 16B-slot
//   ((n>>3)&7) ^ (f&7), elem n&7.  (Unchanged since R0.)

// ---------------------------------------------------------------------------
// Kernel 0 (fp32 mode only): convert ONLY W (65K elems) fp32 -> bf16.
// h is read once per k_wht block, so pre-converting it saved nothing
// (R6 k_cvt's 24-MB h pass was overhead). bf16 mode: early-exit.
// ---------------------------------------------------------------------------
__global__ __launch_bounds__(256)
void k_cvt(const void* __restrict__ hv, const void* __restrict__ Wv,
           bf16* __restrict__ Wb) {
    if (detect_bf16(hv)) return;
    size_t base = ((size_t)blockIdx.x * 256 + threadIdx.x) * 8;
    const float* src = (const float*)Wv + base;
    float4 a = *(const float4*)src;
    float4 b = *(const float4*)(src + 4);
    bf16x8 r;
    r[0]=(bf16)a.x; r[1]=(bf16)a.y; r[2]=(bf16)a.z; r[3]=(bf16)a.w;
    r[4]=(bf16)b.x; r[5]=(bf16)b.y; r[6]=(bf16)b.z; r[7]=(bf16)b.w;
    *(bf16x8*)(Wb + base) = r;
}

// ---------------------------------------------------------------------------
// Kernel A (fused s/t): WhT2 = tiled/swizzled Wh (d_ws); s,t stashed f16 in
// high halves of adjw[token] (t) and adjw[NTOK+token] (s). Masks preserved.
// h: dual path (bf16 direct / fp32 cvt8 — read once, no pre-pass).
// W: always bf16 (pre-converted by k_cvt in fp32 mode).
// WhT2 stores staged through LDS, written as 2 coalesced bf16x8/thread (R8).
// ---------------------------------------------------------------------------
__global__ __launch_bounds__(256)
void k_wht(const void* __restrict__ hv, const void* __restrict__ Wv,
           const bf16* __restrict__ Wcv,
           const void* __restrict__ Wbv, const void* __restrict__ ai_wv,
           const void* __restrict__ ai_bv, const void* __restrict__ aj_wv,
           const void* __restrict__ aj_bv, bf16* __restrict__ WhT2,
           unsigned* __restrict__ adjw) {
    int isb = detect_bf16(hv);
    const bf16* Wb = isb ? (const bf16*)Wv : Wcv;
    int ttile = blockIdx.x;            // 1024 token-tiles of 16
    int fg = threadIdx.x >> 6;         // 4 f-groups of 64
    int lane = threadIdx.x & 63;
    int T0 = ttile * 16;
    int m = lane & 15, quad = lane >> 4;

    __shared__ bf16 stage[F_ * 24];    // [f][token] pitch 24 (48 B, 16-align)
    __shared__ float sred[4][16], tred[4][16];

    f32x4 acc[4];
#pragma unroll
    for (int ft = 0; ft < 4; ++ft) acc[ft] = (f32x4){0.f, 0.f, 0.f, 0.f};

    const bf16* wp = Wb + (size_t)(fg * 64 + m) * F_ + quad * 8;
    if (isb) {
        const bf16* hp = (const bf16*)hv + (size_t)(T0 + m) * F_ + quad * 8;
#pragma unroll
        for (int kk = 0; kk < F_; kk += 32) {
            bf16x8 hf = *(const bf16x8*)(hp + kk);
#pragma unroll
            for (int ft = 0; ft < 4; ++ft) {
                bf16x8 wf = *(const bf16x8*)(wp + (size_t)ft * 16 * F_ + kk);
                acc[ft] = __builtin_amdgcn_mfma_f32_16x16x32_bf16(wf, hf, acc[ft], 0, 0, 0);
            }
        }
    } else {
        const float* hp = (const float*)hv + (size_t)(T0 + m) * F_ + quad * 8;
#pragma unroll
        for (int kk = 0; kk < F_; kk += 32) {
            bf16x8 hf = cvt8(hp + kk);
#pragma unroll
            for (int ft = 0; ft < 4; ++ft) {
                bf16x8 wf = *(const bf16x8*)(wp + (size_t)ft * 16 * F_ + kk);
                acc[ft] = __builtin_amdgcn_mfma_f32_16x16x32_bf16(wf, hf, acc[ft], 0, 0, 0);
            }
        }
    }
    float s_p = 0.f, t_p = 0.f;
#pragma unroll
    for (int ft = 0; ft < 4; ++ft)
#pragma unroll
        for (int r = 0; r < 4; ++r) {
            int f = fg * 64 + ft * 16 + quad * 4 + r;
            float v = acc[ft][r] + ldf(Wbv, f, isb);
            bf16 vb = (bf16)v;
            stage[f * 24 + m] = vb;                  // LDS staging (f-major)
            float vr = (float)vb;                    // rounded, matches WhT2
            s_p += vr * ldf(ai_wv, f, isb);
            t_p += vr * ldf(aj_wv, f, isb);
        }
    s_p += __shfl_down(s_p, 32, 64); s_p += __shfl_down(s_p, 16, 64);
    t_p += __shfl_down(t_p, 32, 64); t_p += __shfl_down(t_p, 16, 64);
    if (lane < 16) { sred[fg][lane] = s_p; tred[fg][lane] = t_p; }
    __syncthreads();

    // ---- vectorized WhT2 store: thread tid owns f-row tid ----
    {
        int f = threadIdx.x;
        bf16x8 pk0 = *(const bf16x8*)(stage + f * 24);      // tokens 0-7
        bf16x8 pk1 = *(const bf16x8*)(stage + f * 24 + 8);  // tokens 8-15
        int b  = T0 >> 11;
        int n0 = T0 & (N_ - 1);
        int jc = n0 >> 6;
        int s0 = (n0 >> 3) & 7;                             // even
        char* rowp = (char*)WhT2 + ((size_t)(b * 32 + jc) * F_ + f) * 128;
        *(bf16x8*)(rowp + (size_t)((s0)     ^ (f & 7)) * 16) = pk0;
        *(bf16x8*)(rowp + (size_t)((s0 + 1) ^ (f & 7)) * 16) = pk1;
    }

    if (threadIdx.x < 16) {
        int tid = threadIdx.x;
        int tok = T0 + tid;
        float ss = (sred[0][tid] + sred[1][tid] + sred[2][tid] + sred[3][tid]
                    + ldf(ai_bv, 0, isb)) * LOG2E;
        float tt = (tred[0][tid] + tred[1][tid] + tred[2][tid] + tred[3][tid]
                    + ldf(aj_bv, 0, isb)) * LOG2E;
        f16 th = (f16)tt, sh = (f16)ss;
        unsigned short tu, su;
        __builtin_memcpy(&tu, &th, 2);
        __builtin_memcpy(&su, &sh, 2);
        unsigned w0 = adjw[tok];
        adjw[tok] = (w0 & 0xFFFFu) | ((unsigned)tu << 16);
        unsigned w1 = adjw[NTOK + tok];
        adjw[NTOK + tok] = (w1 & 0xFFFFu) | ((unsigned)su << 16);
    }
}

__device__ __forceinline__ unsigned char pbits(uint4 a, uint4 b) {
    return (unsigned char)((a.x & 1u) | ((a.y & 1u) << 1) | ((a.z & 1u) << 2) |
                           ((a.w & 1u) << 3) | ((b.x & 1u) << 4) |
                           ((b.y & 1u) << 5) | ((b.z & 1u) << 6) |
                           ((b.w & 1u) << 7));
}

// ---------------------------------------------------------------------------
// Kernel C v9: fused masked-softmax attention + PV + ELU. R=32 rows/block,
// 512 blocks x 256 thr. WAVE-SELF-SUFFICIENT partition: wave w owns f-cols
// [64w, 64w+64). Each wave stages ONLY its own 8-KB B-slice (private dbuf,
// own-vmcnt counted -> provably race-free) and NEVER waits on other waves:
// ZERO in-loop barriers. Each wave computes the full P[32x64] per chunk
// (4x exp2 duplication, VALU headroom exists). adj bit-pack: cooperative,
// 4-chunk groups, double-buffered, ONE barrier per group (8 total vs 33).
// Epilogue: no cross-wave acc reduce (wave owns full K); only l (row sums,
// wave 0's ones-MFMA) broadcast via LDS. XCD pin: b = bid&7.
// ---------------------------------------------------------------------------
__global__ __launch_bounds__(256)
void k_attn(const unsigned* __restrict__ adjw, const bf16* __restrict__ WhT2,
            const void* __restrict__ hv, void* __restrict__ outv) {
    int isb = detect_bf16(hv);
    int bid = blockIdx.x;
    int b = bid & 7, itile = bid >> 3, i0 = itile * 32;
    int tid = threadIdx.x;
    int w = tid >> 6, lane = tid & 63, m = lane & 15, q = lane >> 4;

    __shared__ __align__(16) char smem[71808];
    char* Bw = smem + w * 16384;               // per-wave 16 KB: 2 x 8 KB dbuf
    f16* tLDS = (f16*)(smem + 65536);          // 4 KB
    unsigned char* packb = (unsigned char*)(smem + 69632); // 2 KB [2][32][32]
    float* lred = (float*)(smem + 71680);      // 32 floats

    const char* batch_bytes = (const char*)WhT2 + ((size_t)b * 32) * 32768;

    // ---- prologue ----
#pragma unroll
    for (int k = 0; k < 8; ++k) {
        int idx = k * 256 + tid;
        unsigned wv = adjw[b * N_ + idx];
        unsigned short us = (unsigned short)(wv >> 16);
        f16 tv; __builtin_memcpy(&tv, &us, 2);
        tLDS[idx] = tv;
    }
    float s2i0, s2i1;
    {
        unsigned sw0 = adjw[NTOK + b * N_ + i0 + m];
        unsigned sw1 = adjw[NTOK + b * N_ + i0 + 16 + m];
        unsigned short u0 = (unsigned short)(sw0 >> 16);
        unsigned short u1 = (unsigned short)(sw1 >> 16);
        f16 h0, h1;
        __builtin_memcpy(&h0, &u0, 2); __builtin_memcpy(&h1, &u1, 2);
        s2i0 = (float)h0; s2i1 = (float)h1;
    }

    int prow = tid >> 3, ps = tid & 7;         // 32 rows x 8 j-slices
    const unsigned* arow = adjw + ((size_t)(b * N_ + i0 + prow)) * N_ + ps * 8;
#pragma unroll
    for (int cc = 0; cc < 4; ++cc) {           // pack group 0 (chunks 0-3)
        uint4 x0 = *(const uint4*)(arow + cc * 64);
        uint4 x1 = *(const uint4*)(arow + cc * 64 + 4);
        packb[prow * 32 + cc * 8 + ps] = pbits(x0, x1);
    }
    // stage chunk 0 into own half 0
#pragma unroll
    for (int r = 0; r < 8; ++r) {
        const char* g = batch_bytes + (size_t)w * 8192 + r * 1024 + lane * 16;
        __builtin_amdgcn_global_load_lds(
            (const __attribute__((address_space(1))) unsigned*)g,
            (__attribute__((address_space(3))) unsigned*)(Bw + r * 1024), 16, 0, 0);
    }
    __syncthreads();                           // full drain once

    bf16x8 ones;
#pragma unroll
    for (int k = 0; k < 8; ++k) ones[k] = (bf16)1.0f;

    f32x4 acc[2][4];
#pragma unroll
    for (int rs = 0; rs < 2; ++rs)
#pragma unroll
        for (int ftt = 0; ftt < 4; ++ftt) acc[rs][ftt] = (f32x4){0.f,0.f,0.f,0.f};
    f32x4 accl0 = {0.f,0.f,0.f,0.f}, accl1 = {0.f,0.f,0.f,0.f};

    for (int G = 0; G < 8; ++G) {
        // pack prefetch for group G+1 into buffer (G+1)&1 (its old readers
        // finished before the barrier that ended group G-1)
        if (G < 7) {
#pragma unroll
            for (int cc = 0; cc < 4; ++cc) {
                const unsigned* ap = arow + (size_t)(G + 1) * 256 + cc * 64;
                uint4 x0 = *(const uint4*)ap;
                uint4 x1 = *(const uint4*)(ap + 4);
                packb[(((G + 1) & 1) << 10) + prow * 32 + cc * 8 + ps] =
                    pbits(x0, x1);
            }
        }
#pragma unroll
        for (int cc = 0; cc < 4; ++cc) {
            int c = G * 4 + cc;
            if (c < 31) {                      // stage c+1 into own half
#pragma unroll
                for (int r = 0; r < 8; ++r) {
                    const char* g = batch_bytes + (size_t)(c + 1) * 32768
                                    + (size_t)w * 8192 + r * 1024 + lane * 16;
                    __builtin_amdgcn_global_load_lds(
                        (const __attribute__((address_space(1))) unsigned*)g,
                        (__attribute__((address_space(3))) unsigned*)
                            (Bw + ((c + 1) & 1) * 8192 + r * 1024), 16, 0, 0);
                }
                asm volatile("s_waitcnt vmcnt(8)" ::: "memory");
            } else {
                asm volatile("s_waitcnt vmcnt(0)" ::: "memory");
            }
            __builtin_amdgcn_sched_barrier(0);

            // ---- compute chunk c (no cross-wave deps) ----
            const unsigned char* pc = packb + ((G & 1) << 10) + cc * 8;
            unsigned long long pb0 = *(const unsigned long long*)(pc + m * 32);
            unsigned long long pb1 =
                *(const unsigned long long*)(pc + (m + 16) * 32);
            f16x8 tv0 = *(const f16x8*)(tLDS + c * 64 + q * 8);
            f16x8 tv1 = *(const f16x8*)(tLDS + c * 64 + 32 + q * 8);

            bf16x8 af[2][2];
#pragma unroll
            for (int rs = 0; rs < 2; ++rs) {
                float s2 = rs ? s2i1 : s2i0;
                unsigned long long pb = rs ? pb1 : pb0;
#pragma unroll
                for (int jh = 0; jh < 2; ++jh) {
                    unsigned bits = (unsigned)(pb >> ((jh * 4 + q) * 8)) & 0xFFu;
                    f16x8 tv = jh ? tv1 : tv0;
#pragma unroll
                    for (int qq = 0; qq < 8; ++qq) {
                        float x = s2 + (float)tv[qq];
                        x = fmaxf(x, 0.2f * x);        // LeakyReLU (log2-scaled)
                        float pv = ((bits >> qq) & 1u)
                                       ? __builtin_amdgcn_exp2f(x) : 0.f;
                        af[rs][jh][qq] = (bf16)pv;
                    }
                }
            }
            const char* Bc = Bw + (c & 1) * 8192;
#pragma unroll
            for (int jh = 0; jh < 2; ++jh)
#pragma unroll
                for (int ftt = 0; ftt < 4; ++ftt) {
                    int psl = (jh * 4 + q) ^ (m & 7);
                    bf16x8 bfr = *(const bf16x8*)
                        (Bc + (ftt * 16 + m) * 128 + psl * 16);
                    acc[0][ftt] = __builtin_amdgcn_mfma_f32_16x16x32_bf16(
                        af[0][jh], bfr, acc[0][ftt], 0, 0, 0);
                    acc[1][ftt] = __builtin_amdgcn_mfma_f32_16x16x32_bf16(
                        af[1][jh], bfr, acc[1][ftt], 0, 0, 0);
                }
            if (w == 0) {                      // row sums (l), wave 0 only
                accl0 = __builtin_amdgcn_mfma_f32_16x16x32_bf16(af[0][0], ones, accl0, 0, 0, 0);
                accl0 = __builtin_amdgcn_mfma_f32_16x16x32_bf16(af[0][1], ones, accl0, 0, 0, 0);
                accl1 = __builtin_amdgcn_mfma_f32_16x16x32_bf16(af[1][0], ones, accl1, 0, 0, 0);
                accl1 = __builtin_amdgcn_mfma_f32_16x16x32_bf16(af[1][1], ones, accl1, 0, 0, 0);
            }
        }
        // group-end barrier: pack writes visible; own DMAs stay in flight
        asm volatile("s_waitcnt lgkmcnt(0)" ::: "memory");
        __builtin_amdgcn_s_barrier();
        __builtin_amdgcn_sched_barrier(0);
    }

    // ---- epilogue: broadcast l, normalize, ELU, store ----
    if (w == 0 && m == 0) {
#pragma unroll
        for (int r = 0; r < 4; ++r) {
            lred[q * 4 + r]      = accl0[r];
            lred[16 + q * 4 + r] = accl1[r];
        }
    }
    __syncthreads();
#pragma unroll
    for (int rs = 0; rs < 2; ++rs)
#pragma unroll
        for (int r = 0; r < 4; ++r) {
            int rr = rs * 16 + q * 4 + r;
            float lf = lred[rr];
            float rl = (lf > 0.f) ? (1.f / lf) : 0.f;
            size_t ob = ((size_t)b * N_ + i0 + rr) * F_;
#pragma unroll
            for (int ftt = 0; ftt < 4; ++ftt) {
                int f = w * 64 + ftt * 16 + m;
                float v = acc[rs][ftt][r] * rl;
                v = (v > 0.f) ? v : (__builtin_amdgcn_exp2f(v * LOG2E) - 1.f);
                if (isb) ((bf16*)outv)[ob + f] = (bf16)v;
                else     ((float*)outv)[ob + f] = v;
            }
        }
}

// ---------------------------------------------------------------------------
extern "C" void kernel_launch(void* const* d_in, const int* in_sizes, int n_in,
                              void* d_out, int out_size, void* d_ws, size_t ws_size,
                              hipStream_t stream) {
    (void)in_sizes; (void)n_in; (void)out_size; (void)ws_size;
    const void* h    = d_in[0];
    unsigned*   adjw = (unsigned*)d_in[1];   // int32 adj; high 16 bits reused
    const void* W_w  = d_in[2];
    const void* W_b  = d_in[3];
    const void* ai_w = d_in[4];
    const void* ai_b = d_in[5];
    const void* aj_w = d_in[6];
    const void* aj_b = d_in[7];

    bf16* WhT2 = (bf16*)d_ws;                            // 8 MiB
    bf16* Wcv  = (bf16*)((char*)d_ws + (8 << 20));       // 128 KiB W bf16

    k_cvt <<<dim3(32),   dim3(256), 0, stream>>>(h, W_w, Wcv);
    k_wht <<<dim3(1024), dim3(256), 0, stream>>>(h, W_w, Wcv, W_b,
                                                 ai_w, ai_b, aj_w, aj_b,
                                                 WhT2, adjw);
    k_attn<<<dim3(512),  dim3(256), 0, stream>>>(adjw, WhT2, h, d_out);
}

// Round 10
// 263.140 us; speedup vs baseline: 1.0787x; 1.0787x over previous
//
#include <hip/hip_runtime.h>

typedef __bf16 bf16;
typedef _Float16 f16;
typedef __bf16 bf16x8 __attribute__((ext_vector_type(8)));
typedef _Float16 f16x8 __attribute__((ext_vector_type(8)));
typedef float  f32x4  __attribute__((ext_vector_type(4)));

#define B_  8
#define N_  2048
#define F_  256
#define NTOK (B_ * N_)
#define NW   (F_ * F_)              // 65,536 W elements
static constexpr float LOG2E = 1.44269504088896f;

// ---------------------------------------------------------------------------
// dtype detector (bf16-packed vs fp32). Wave-uniform. Proven rounds 3-7.
// ---------------------------------------------------------------------------
__device__ __forceinline__ int detect_bf16(const void* h) {
    const unsigned* hw = (const unsigned*)h;
    unsigned w = hw[threadIdx.x & 63];
    unsigned ex = (w >> 7) & 0xFFu;
    unsigned long long b = __ballot(ex > 100u && ex < 150u);
    return __popcll(b) >= 40;
}

__device__ __forceinline__ float ldf(const void* p, int i, int isb) {
    return isb ? (float)((const bf16*)p)[i] : ((const float*)p)[i];
}

__device__ __forceinline__ bf16x8 cvt8(const float* p) {
    float4 a = *(const float4*)p;
    float4 b = *(const float4*)(p + 4);
    bf16x8 r;
    r[0]=(bf16)a.x; r[1]=(bf16)a.y; r[2]=(bf16)a.z; r[3]=(bf16)a.w;
    r[4]=(bf16)b.x; r[5]=(bf16)b.y; r[6]=(bf16)b.z; r[7]=(bf16)b.w;
    return r;
}

// WhT2 tiled layout (LDS-bank-XOR baked in), byte address for (b, f, n):
//   tile = b*32 + (n>>6); within tile: row f (128 B), phys 16B-slot
//   ((n>>3)&7) ^ (f&7), elem n&7.  (Unchanged since R0.)

// ---------------------------------------------------------------------------
// Kernel 0 (fp32 mode only): convert ONLY W (65K elems) fp32 -> bf16.
// h is read once per k_wht block so pre-converting it saves nothing.
// bf16 mode: early-exit.
// ---------------------------------------------------------------------------
__global__ __launch_bounds__(256)
void k_cvt(const void* __restrict__ hv, const void* __restrict__ Wv,
           bf16* __restrict__ Wb) {
    if (detect_bf16(hv)) return;
    size_t base = ((size_t)blockIdx.x * 256 + threadIdx.x) * 8;
    const float* src = (const float*)Wv + base;
    float4 a = *(const float4*)src;
    float4 b = *(const float4*)(src + 4);
    bf16x8 r;
    r[0]=(bf16)a.x; r[1]=(bf16)a.y; r[2]=(bf16)a.z; r[3]=(bf16)a.w;
    r[4]=(bf16)b.x; r[5]=(bf16)b.y; r[6]=(bf16)b.z; r[7]=(bf16)b.w;
    *(bf16x8*)(Wb + base) = r;
}

// ---------------------------------------------------------------------------
// Kernel A (fused s/t): WhT2 = tiled/swizzled Wh (d_ws); s,t stashed f16 in
// high halves of adjw[token] (t) and adjw[NTOK+token] (s). Masks preserved.
// h: dual path (bf16 direct / fp32 cvt8 — read once). W: always bf16.
// WhT2 stores staged through LDS, written as 2 coalesced bf16x8/thread.
// (R9 k_wht, proven passing.)
// ---------------------------------------------------------------------------
__global__ __launch_bounds__(256)
void k_wht(const void* __restrict__ hv, const void* __restrict__ Wv,
           const bf16* __restrict__ Wcv,
           const void* __restrict__ Wbv, const void* __restrict__ ai_wv,
           const void* __restrict__ ai_bv, const void* __restrict__ aj_wv,
           const void* __restrict__ aj_bv, bf16* __restrict__ WhT2,
           unsigned* __restrict__ adjw) {
    int isb = detect_bf16(hv);
    const bf16* Wb = isb ? (const bf16*)Wv : Wcv;
    int ttile = blockIdx.x;            // 1024 token-tiles of 16
    int fg = threadIdx.x >> 6;         // 4 f-groups of 64
    int lane = threadIdx.x & 63;
    int T0 = ttile * 16;
    int m = lane & 15, quad = lane >> 4;

    __shared__ bf16 stage[F_ * 24];    // [f][token] pitch 24 (48 B, 16-align)
    __shared__ float sred[4][16], tred[4][16];

    f32x4 acc[4];
#pragma unroll
    for (int ft = 0; ft < 4; ++ft) acc[ft] = (f32x4){0.f, 0.f, 0.f, 0.f};

    const bf16* wp = Wb + (size_t)(fg * 64 + m) * F_ + quad * 8;
    if (isb) {
        const bf16* hp = (const bf16*)hv + (size_t)(T0 + m) * F_ + quad * 8;
#pragma unroll
        for (int kk = 0; kk < F_; kk += 32) {
            bf16x8 hf = *(const bf16x8*)(hp + kk);
#pragma unroll
            for (int ft = 0; ft < 4; ++ft) {
                bf16x8 wf = *(const bf16x8*)(wp + (size_t)ft * 16 * F_ + kk);
                acc[ft] = __builtin_amdgcn_mfma_f32_16x16x32_bf16(wf, hf, acc[ft], 0, 0, 0);
            }
        }
    } else {
        const float* hp = (const float*)hv + (size_t)(T0 + m) * F_ + quad * 8;
#pragma unroll
        for (int kk = 0; kk < F_; kk += 32) {
            bf16x8 hf = cvt8(hp + kk);
#pragma unroll
            for (int ft = 0; ft < 4; ++ft) {
                bf16x8 wf = *(const bf16x8*)(wp + (size_t)ft * 16 * F_ + kk);
                acc[ft] = __builtin_amdgcn_mfma_f32_16x16x32_bf16(wf, hf, acc[ft], 0, 0, 0);
            }
        }
    }
    float s_p = 0.f, t_p = 0.f;
#pragma unroll
    for (int ft = 0; ft < 4; ++ft)
#pragma unroll
        for (int r = 0; r < 4; ++r) {
            int f = fg * 64 + ft * 16 + quad * 4 + r;
            float v = acc[ft][r] + ldf(Wbv, f, isb);
            bf16 vb = (bf16)v;
            stage[f * 24 + m] = vb;                  // LDS staging (f-major)
            float vr = (float)vb;                    // rounded, matches WhT2
            s_p += vr * ldf(ai_wv, f, isb);
            t_p += vr * ldf(aj_wv, f, isb);
        }
    s_p += __shfl_down(s_p, 32, 64); s_p += __shfl_down(s_p, 16, 64);
    t_p += __shfl_down(t_p, 32, 64); t_p += __shfl_down(t_p, 16, 64);
    if (lane < 16) { sred[fg][lane] = s_p; tred[fg][lane] = t_p; }
    __syncthreads();

    // ---- vectorized WhT2 store: thread tid owns f-row tid ----
    {
        int f = threadIdx.x;
        bf16x8 pk0 = *(const bf16x8*)(stage + f * 24);      // tokens 0-7
        bf16x8 pk1 = *(const bf16x8*)(stage + f * 24 + 8);  // tokens 8-15
        int b  = T0 >> 11;
        int n0 = T0 & (N_ - 1);
        int jc = n0 >> 6;
        int s0 = (n0 >> 3) & 7;                             // even
        char* rowp = (char*)WhT2 + ((size_t)(b * 32 + jc) * F_ + f) * 128;
        *(bf16x8*)(rowp + (size_t)((s0)     ^ (f & 7)) * 16) = pk0;
        *(bf16x8*)(rowp + (size_t)((s0 + 1) ^ (f & 7)) * 16) = pk1;
    }

    if (threadIdx.x < 16) {
        int tid = threadIdx.x;
        int tok = T0 + tid;
        float ss = (sred[0][tid] + sred[1][tid] + sred[2][tid] + sred[3][tid]
                    + ldf(ai_bv, 0, isb)) * LOG2E;
        float tt = (tred[0][tid] + tred[1][tid] + tred[2][tid] + tred[3][tid]
                    + ldf(aj_bv, 0, isb)) * LOG2E;
        f16 th = (f16)tt, sh = (f16)ss;
        unsigned short tu, su;
        __builtin_memcpy(&tu, &th, 2);
        __builtin_memcpy(&su, &sh, 2);
        unsigned w0 = adjw[tok];
        adjw[tok] = (w0 & 0xFFFFu) | ((unsigned)tu << 16);
        unsigned w1 = adjw[NTOK + tok];
        adjw[NTOK + tok] = (w1 & 0xFFFFu) | ((unsigned)su << 16);
    }
}

__device__ __forceinline__ unsigned char pbits(uint4 a, uint4 b) {
    return (unsigned char)((a.x & 1u) | ((a.y & 1u) << 1) | ((a.z & 1u) << 2) |
                           ((a.w & 1u) << 3) | ((b.x & 1u) << 4) |
                           ((b.y & 1u) << 5) | ((b.z & 1u) << 6) |
                           ((b.w & 1u) << 7));
}

// stage one 32 KB chunk tile: PURE contiguous copy (swizzle pre-baked).
// 4 waves x 8 instrs x (64 lanes x 16 B contiguous).
__device__ __forceinline__ void stageB(const bf16* tile, char* dst,
                                       int w, int lane) {
#pragma unroll
    for (int r = 0; r < 8; ++r) {
        int off = (w * 8 + r) * 1024;               // bytes, wave-uniform
        const bf16* g = tile + off / 2 + lane * 8;
        __builtin_amdgcn_global_load_lds(
            (const __attribute__((address_space(1))) unsigned*)g,
            (__attribute__((address_space(3))) unsigned*)(dst + off),
            16, 0, 0);
    }
}

// ---------------------------------------------------------------------------
// Kernel C: fused masked-softmax attention + PV + ELU. R=32 rows/block,
// 512 blocks (2/CU) x 256 thr (4 waves = 2 m-tiles x 2 j-halves).
// j in 32 chunks of 64: B tile DMA'd contiguously (dbuf); adj bit-packed to
// LDS (dbuf); l via all-ones MFMA. One __syncthreads per chunk.
// XCD pin: b = bid&7 (blocks round-robin over 8 XCDs -> XCD k serves batch
// k; its 1-MB WhT2 slice + adj stream stay in the local 4-MB L2).
// BIT-EXACT the R6 best (~70 us); R7/R8/R9 restructures all regressed.
// ---------------------------------------------------------------------------
__global__ __launch_bounds__(256)
void k_attn(const unsigned* __restrict__ adjw, const bf16* __restrict__ WhT2,
            const void* __restrict__ hv, void* __restrict__ outv) {
    int isb = detect_bf16(hv);
    int bid = blockIdx.x;
    int b = bid & 7, itile = bid >> 3, i0 = itile * 32;
    int tid = threadIdx.x;
    int w = tid >> 6, lane = tid & 63, m = lane & 15, q = lane >> 4;
    int mt = w >> 1, jh = w & 1;

    __shared__ __align__(16) char smem[70656];
    char* Bbuf0 = smem;                                    // 32 KB
    char* Bbuf1 = smem + 32768;                            // 32 KB
    f16* tLDS   = (f16*)(smem + 65536);                    // 4 KB
    unsigned char* pack0 = (unsigned char*)(smem + 69632); // 256 B
    unsigned char* pack1 = (unsigned char*)(smem + 69888); // 256 B
    float* red  = (float*)smem;           // epilogue overlay [32][257]

    const bf16* batch_tiles = WhT2 + ((size_t)b * 32) * F_ * 64;

    // ---- prologue ----
#pragma unroll
    for (int k = 0; k < 8; ++k) {
        int idx = k * 256 + tid;
        unsigned wv = adjw[b * N_ + idx];
        unsigned short us = (unsigned short)(wv >> 16);
        f16 tv; __builtin_memcpy(&tv, &us, 2);
        tLDS[idx] = tv;
    }
    int row = i0 + mt * 16 + m;
    unsigned swd = adjw[NTOK + b * N_ + row];
    unsigned short su = (unsigned short)(swd >> 16);
    f16 sh; __builtin_memcpy(&sh, &su, 2);
    float s2i = (float)sh;

    int prow = tid >> 3, ps = tid & 7;         // 32 rows x 8 bytes
    const unsigned* arow = adjw + ((size_t)(b * N_ + i0 + prow)) * N_ + ps * 8;
    {
        uint4 x0 = *(const uint4*)arow, x1 = *(const uint4*)(arow + 4);
        pack0[prow * 8 + ps] = pbits(x0, x1);
    }
    stageB(batch_tiles, Bbuf0, w, lane);
    __syncthreads();

    bf16x8 ones;
#pragma unroll
    for (int k = 0; k < 8; ++k) ones[k] = (bf16)1.0f;

    f32x4 acc[16];
#pragma unroll
    for (int ft = 0; ft < 16; ++ft) acc[ft] = (f32x4){0.f, 0.f, 0.f, 0.f};
    f32x4 acc_l = {0.f, 0.f, 0.f, 0.f};

    for (int c = 0; c < 32; ++c) {
        char* Bcur = (c & 1) ? Bbuf1 : Bbuf0;
        unsigned char* pcur = (c & 1) ? pack1 : pack0;
        uint4 aw0, aw1;
        bool pre = (c < 31);
        if (pre) {
            stageB(batch_tiles + (size_t)(c + 1) * F_ * 64,
                   (c & 1) ? Bbuf0 : Bbuf1, w, lane);
            aw0 = *(const uint4*)(arow + (size_t)(c + 1) * 64);
            aw1 = *(const uint4*)(arow + (size_t)(c + 1) * 64 + 4);
        }
        // ---- compute chunk c ----
        unsigned long long pb64 =
            *(const unsigned long long*)(pcur + (mt * 16 + m) * 8);
        unsigned bits8 = (unsigned)(pb64 >> ((jh * 4 + q) * 8)) & 0xFFu;
        f16x8 tv = *(const f16x8*)(tLDS + c * 64 + jh * 32 + q * 8);

        bf16x8 af;
#pragma unroll
        for (int qq = 0; qq < 8; ++qq) {
            float x = s2i + (float)tv[qq];
            x = fmaxf(x, 0.2f * x);                    // LeakyReLU (log2-scaled)
            float pv = ((bits8 >> qq) & 1u) ? __builtin_amdgcn_exp2f(x) : 0.f;
            af[qq] = (bf16)pv;
        }
        int sbase = (jh * 4 + q);                      // logical slot
#pragma unroll
        for (int ft = 0; ft < 16; ++ft) {
            int fr = ft * 16 + m;
            int psl = sbase ^ (m & 7);                 // phys slot (pre-baked)
            bf16x8 bfr = *(const bf16x8*)(Bcur + fr * 128 + psl * 16);
            acc[ft] = __builtin_amdgcn_mfma_f32_16x16x32_bf16(af, bfr, acc[ft], 0, 0, 0);
        }
        acc_l = __builtin_amdgcn_mfma_f32_16x16x32_bf16(af, ones, acc_l, 0, 0, 0);
        if (pre)
            ((c & 1) ? pack0 : pack1)[prow * 8 + ps] = pbits(aw0, aw1);
        __syncthreads();
    }

    // ---- epilogue: cross-jh reduce via LDS overlay ----
    if (jh == 1) {
#pragma unroll
        for (int r = 0; r < 4; ++r) {
            int rr = mt * 16 + q * 4 + r;
#pragma unroll
            for (int ft = 0; ft < 16; ++ft)
                red[rr * 257 + ft * 16 + m] = acc[ft][r];
            if (m == 0) red[rr * 257 + 256] = acc_l[r];
        }
    }
    __syncthreads();
    if (jh == 0) {
#pragma unroll
        for (int r = 0; r < 4; ++r) {
            int rr = mt * 16 + q * 4 + r;
            float lf = acc_l[r] + red[rr * 257 + 256];
            float rl = (lf > 0.f) ? (1.f / lf) : 0.f;
            size_t ob = ((size_t)b * N_ + i0 + rr) * F_;
#pragma unroll
            for (int ft = 0; ft < 16; ++ft) {
                int f = ft * 16 + m;
                float v = acc[ft][r] + red[rr * 257 + f];
                v *= rl;
                v = (v > 0.f) ? v : (__builtin_amdgcn_exp2f(v * LOG2E) - 1.f);
                if (isb) ((bf16*)outv)[ob + f] = (bf16)v;
                else     ((float*)outv)[ob + f] = v;
            }
        }
    }
}

// ---------------------------------------------------------------------------
extern "C" void kernel_launch(void* const* d_in, const int* in_sizes, int n_in,
                              void* d_out, int out_size, void* d_ws, size_t ws_size,
                              hipStream_t stream) {
    (void)in_sizes; (void)n_in; (void)out_size; (void)ws_size;
    const void* h    = d_in[0];
    unsigned*   adjw = (unsigned*)d_in[1];   // int32 adj; high 16 bits reused
    const void* W_w  = d_in[2];
    const void* W_b  = d_in[3];
    const void* ai_w = d_in[4];
    const void* ai_b = d_in[5];
    const void* aj_w = d_in[6];
    const void* aj_b = d_in[7];

    bf16* WhT2 = (bf16*)d_ws;                            // 8 MiB
    bf16* Wcv  = (bf16*)((char*)d_ws + (8 << 20));       // 128 KiB W bf16

    k_cvt <<<dim3(32),   dim3(256), 0, stream>>>(h, W_w, Wcv);
    k_wht <<<dim3(1024), dim3(256), 0, stream>>>(h, W_w, Wcv, W_b,
                                                 ai_w, ai_b, aj_w, aj_b,
                                                 WhT2, adjw);
    k_attn<<<dim3(512),  dim3(256), 0, stream>>>(adjw, WhT2, h, d_out);
}